// Round 2
// baseline (2435.478 us; speedup 1.0000x reference)
//
#include <hip/hip_runtime.h>
#include <hip/hip_bf16.h>

#define NNODES 100000
#define NEG 0.2f
#define FEPS 1e-16f

// monotonic encode of float into uint for atomicMax-based float max
__device__ __forceinline__ unsigned enc_f(float x) {
    unsigned u = __float_as_uint(x);
    return (u & 0x80000000u) ? ~u : (u | 0x80000000u);
}
__device__ __forceinline__ float dec_f(unsigned e) {
    return __uint_as_float((e & 0x80000000u) ? (e ^ 0x80000000u) : ~e);
}

// GEMM: A [N x K] * W [K x 128] -> out [N x 128].
// W staged in LDS 32 rows at a time (16KB) + 16-row A tile (<=8KB).
template <int K>
__global__ __launch_bounds__(256) void gemm_kernel(const float* __restrict__ A,
                                                   const float* __restrict__ W,
                                                   float* __restrict__ out, int N) {
    __shared__ float Ws[32 * 128];
    __shared__ float xs[16 * K];
    const int tid = threadIdx.x;
    const int row0 = blockIdx.x * 16;
    for (int i = tid; i < 16 * K; i += 256) {
        int r = i / K, k = i - r * K;
        int row = row0 + r;
        xs[i] = (row < N) ? A[(size_t)row * K + k] : 0.f;
    }
    const int c = tid & 127;
    const int half = tid >> 7;  // rows half*8 .. half*8+7
    float acc[8];
#pragma unroll
    for (int r = 0; r < 8; r++) acc[r] = 0.f;
    for (int k0 = 0; k0 < K; k0 += 32) {
        __syncthreads();
        for (int i = tid; i < 32 * 128; i += 256) Ws[i] = W[k0 * 128 + i];
        __syncthreads();
#pragma unroll 8
        for (int k = 0; k < 32; k++) {
            float wv = Ws[k * 128 + c];
#pragma unroll
            for (int r = 0; r < 8; r++) acc[r] += xs[(half * 8 + r) * K + k0 + k] * wv;
        }
    }
#pragma unroll
    for (int r = 0; r < 8; r++) {
        int row = row0 + half * 8 + r;
        if (row < N) out[(size_t)row * 128 + c] = acc[r];
    }
}

// per-node attention scalars: a_src[n][h] = sum_c h[n][h*64+c]*att_s[h*64+c] (same for dst)
__global__ __launch_bounds__(256) void acompute_kernel(const float* __restrict__ h,
                                                       const float* __restrict__ att_s,
                                                       const float* __restrict__ att_d,
                                                       float* __restrict__ a_src,
                                                       float* __restrict__ a_dst, int N) {
    int node = blockIdx.x * 4 + (threadIdx.x >> 6);
    int lane = threadIdx.x & 63;
    if (node >= N) return;
    float v0 = h[(size_t)node * 128 + lane];
    float v1 = h[(size_t)node * 128 + 64 + lane];
    float s0 = v0 * att_s[lane];
    float s1 = v1 * att_s[64 + lane];
    float d0 = v0 * att_d[lane];
    float d1 = v1 * att_d[64 + lane];
    for (int off = 32; off; off >>= 1) {
        s0 += __shfl_xor(s0, off);
        s1 += __shfl_xor(s1, off);
        d0 += __shfl_xor(d0, off);
        d1 += __shfl_xor(d1, off);
    }
    if (lane == 0) {
        a_src[node * 2] = s0;
        a_src[node * 2 + 1] = s1;
        a_dst[node * 2] = d0;
        a_dst[node * 2 + 1] = d1;
    }
}

__global__ __launch_bounds__(256) void edgemax_kernel(const int* __restrict__ ei, int E_in,
                                                      int E_tot,
                                                      const float* __restrict__ a_src,
                                                      const float* __restrict__ a_dst,
                                                      unsigned* __restrict__ amax) {
    int e = blockIdx.x * 256 + threadIdx.x;
    if (e >= E_tot) return;
    int s, d;
    if (e < E_in) {
        s = ei[e];
        d = ei[E_in + e];
    } else {
        s = d = e - E_in;
    }
#pragma unroll
    for (int hh = 0; hh < 2; hh++) {
        float al = a_src[s * 2 + hh] + a_dst[d * 2 + hh];
        al = al > 0.f ? al : NEG * al;
        atomicMax(&amax[d * 2 + hh], enc_f(al));
    }
}

__global__ __launch_bounds__(256) void edgedenom_kernel(const int* __restrict__ ei, int E_in,
                                                        int E_tot,
                                                        const float* __restrict__ a_src,
                                                        const float* __restrict__ a_dst,
                                                        const unsigned* __restrict__ amax,
                                                        float* __restrict__ denom) {
    int e = blockIdx.x * 256 + threadIdx.x;
    if (e >= E_tot) return;
    int s, d;
    if (e < E_in) {
        s = ei[e];
        d = ei[E_in + e];
    } else {
        s = d = e - E_in;
    }
#pragma unroll
    for (int hh = 0; hh < 2; hh++) {
        float al = a_src[s * 2 + hh] + a_dst[d * 2 + hh];
        al = al > 0.f ? al : NEG * al;
        float ex = expf(al - dec_f(amax[d * 2 + hh]));
        atomicAdd(&denom[d * 2 + hh], ex);
    }
}

// acc[dst][c] += alpha(e, head(c)) * h[src][c]   (c in [0,128), head = c>>6)
__global__ __launch_bounds__(256) void scatter_kernel(const int* __restrict__ ei, int E_in,
                                                      int E_tot,
                                                      const float* __restrict__ a_src,
                                                      const float* __restrict__ a_dst,
                                                      const unsigned* __restrict__ amax,
                                                      const float* __restrict__ denom,
                                                      const float* __restrict__ h,
                                                      float* __restrict__ acc) {
    int tid = blockIdx.x * 256 + threadIdx.x;
    int total = E_tot * 128;
    if (tid >= total) return;
    int e = tid >> 7;
    int c = tid & 127;
    int hh = c >> 6;
    int s, d;
    if (e < E_in) {
        s = ei[e];
        d = ei[E_in + e];
    } else {
        s = d = e - E_in;
    }
    float al = a_src[s * 2 + hh] + a_dst[d * 2 + hh];
    al = al > 0.f ? al : NEG * al;
    float ex = expf(al - dec_f(amax[d * 2 + hh]));
    float w = ex / (denom[d * 2 + hh] + FEPS);
    atomicAdd(&acc[(size_t)d * 128 + c], w * h[(size_t)s * 128 + c]);
}

// x2[n][c] = elu(0.5*(acc[n][c]+acc[n][64+c]) + b[c])
__global__ __launch_bounds__(256) void fin1_kernel(const float* __restrict__ acc,
                                                   const float* __restrict__ b,
                                                   float* __restrict__ x2, int N) {
    int tid = blockIdx.x * 256 + threadIdx.x;
    if (tid >= N * 64) return;
    int n = tid >> 6, c = tid & 63;
    float v = 0.5f * (acc[(size_t)n * 128 + c] + acc[(size_t)n * 128 + 64 + c]) + b[c];
    x2[tid] = v > 0.f ? v : expf(v) - 1.f;
}

// out[n] = sum_c elu(0.5*(acc[n][c]+acc[n][64+c]) + b[c]) * lin_w[c] + lin_b
__global__ __launch_bounds__(256) void fin2_kernel(const float* __restrict__ acc,
                                                   const float* __restrict__ b,
                                                   const float* __restrict__ lin_w,
                                                   const float* __restrict__ lin_b,
                                                   float* __restrict__ out, int N) {
    int n = blockIdx.x * 4 + (threadIdx.x >> 6);
    int c = threadIdx.x & 63;
    if (n >= N) return;
    float v = 0.5f * (acc[(size_t)n * 128 + c] + acc[(size_t)n * 128 + 64 + c]) + b[c];
    v = v > 0.f ? v : expf(v) - 1.f;
    float p = v * lin_w[c];
    for (int off = 32; off; off >>= 1) p += __shfl_xor(p, off);
    if (c == 0) out[n] = p + lin_b[0];
}

extern "C" void kernel_launch(void* const* d_in, const int* in_sizes, int n_in,
                              void* d_out, int out_size, void* d_ws, size_t ws_size,
                              hipStream_t stream) {
    const float* x = (const float*)d_in[0];
    const int* ei = (const int*)d_in[1];
    const float* W1 = (const float*)d_in[2];
    const float* as1 = (const float*)d_in[3];
    const float* ad1 = (const float*)d_in[4];
    const float* b1 = (const float*)d_in[5];
    const float* W2 = (const float*)d_in[6];
    const float* as2 = (const float*)d_in[7];
    const float* ad2 = (const float*)d_in[8];
    const float* b2 = (const float*)d_in[9];
    const float* lin_w = (const float*)d_in[10];
    const float* lin_b = (const float*)d_in[11];
    float* out = (float*)d_out;

    const int N = NNODES;
    const int E_in = in_sizes[1] / 2;
    const int E_tot = E_in + N;

    char* ws = (char*)d_ws;
    size_t off = 0;
    auto alloc = [&](size_t bytes) {
        void* p = ws + off;
        off += (bytes + 255) & ~(size_t)255;
        return p;
    };
    float* h = (float*)alloc((size_t)N * 128 * 4);
    float* x2 = (float*)alloc((size_t)N * 64 * 4);
    float* a_src = (float*)alloc((size_t)N * 2 * 4);
    float* a_dst = (float*)alloc((size_t)N * 2 * 4);
    float* acc = (float*)alloc((size_t)N * 128 * 4);
    unsigned* amax = (unsigned*)alloc((size_t)N * 2 * 4);
    float* denom = (float*)alloc((size_t)N * 2 * 4);

    const int edge_blocks = (E_tot + 255) / 256;
    const int scat_blocks = (E_tot * 128 + 255) / 256;  // 218M threads, fits int

    // ---- layer 1 ----
    hipLaunchKernelGGL((gemm_kernel<128>), dim3((N + 15) / 16), dim3(256), 0, stream, x, W1, h, N);
    hipLaunchKernelGGL(acompute_kernel, dim3((N + 3) / 4), dim3(256), 0, stream, h, as1, ad1,
                       a_src, a_dst, N);
    hipMemsetAsync(acc, 0, (size_t)N * 128 * 4, stream);
    hipMemsetAsync(amax, 0, (size_t)N * 2 * 4, stream);
    hipMemsetAsync(denom, 0, (size_t)N * 2 * 4, stream);
    hipLaunchKernelGGL(edgemax_kernel, dim3(edge_blocks), dim3(256), 0, stream, ei, E_in, E_tot,
                       a_src, a_dst, amax);
    hipLaunchKernelGGL(edgedenom_kernel, dim3(edge_blocks), dim3(256), 0, stream, ei, E_in, E_tot,
                       a_src, a_dst, amax, denom);
    hipLaunchKernelGGL(scatter_kernel, dim3(scat_blocks), dim3(256), 0, stream, ei, E_in, E_tot,
                       a_src, a_dst, amax, denom, h, acc);
    hipLaunchKernelGGL(fin1_kernel, dim3((N * 64 + 255) / 256), dim3(256), 0, stream, acc, b1, x2,
                       N);

    // ---- layer 2 ----
    hipLaunchKernelGGL((gemm_kernel<64>), dim3((N + 15) / 16), dim3(256), 0, stream, x2, W2, h, N);
    hipLaunchKernelGGL(acompute_kernel, dim3((N + 3) / 4), dim3(256), 0, stream, h, as2, ad2,
                       a_src, a_dst, N);
    hipMemsetAsync(acc, 0, (size_t)N * 128 * 4, stream);
    hipMemsetAsync(amax, 0, (size_t)N * 2 * 4, stream);
    hipMemsetAsync(denom, 0, (size_t)N * 2 * 4, stream);
    hipLaunchKernelGGL(edgemax_kernel, dim3(edge_blocks), dim3(256), 0, stream, ei, E_in, E_tot,
                       a_src, a_dst, amax);
    hipLaunchKernelGGL(edgedenom_kernel, dim3(edge_blocks), dim3(256), 0, stream, ei, E_in, E_tot,
                       a_src, a_dst, amax, denom);
    hipLaunchKernelGGL(scatter_kernel, dim3(scat_blocks), dim3(256), 0, stream, ei, E_in, E_tot,
                       a_src, a_dst, amax, denom, h, acc);
    hipLaunchKernelGGL(fin2_kernel, dim3((N + 3) / 4), dim3(256), 0, stream, acc, b2, lin_w,
                       lin_b, out, N);
}

// Round 3
// 898.984 us; speedup vs baseline: 2.7091x; 2.7091x over previous
//
#include <hip/hip_runtime.h>
#include <hip/hip_bf16.h>

#define NNODES 100000
#define NEG 0.2f
#define FEPS 1e-16f

// ---------------- GEMM: A [N x K] * W [K x 128] -> out [N x 128] ----------------
// W staged in LDS 32 rows at a time (16KB) + 16-row A tile (<=8KB).
template <int K>
__global__ __launch_bounds__(256) void gemm_kernel(const float* __restrict__ A,
                                                   const float* __restrict__ W,
                                                   float* __restrict__ out, int N) {
    __shared__ float Ws[32 * 128];
    __shared__ float xs[16 * K];
    const int tid = threadIdx.x;
    const int row0 = blockIdx.x * 16;
    for (int i = tid; i < 16 * K; i += 256) {
        int r = i / K, k = i - r * K;
        int row = row0 + r;
        xs[i] = (row < N) ? A[(size_t)row * K + k] : 0.f;
    }
    const int c = tid & 127;
    const int half = tid >> 7;
    float acc[8];
#pragma unroll
    for (int r = 0; r < 8; r++) acc[r] = 0.f;
    for (int k0 = 0; k0 < K; k0 += 32) {
        __syncthreads();
        for (int i = tid; i < 32 * 128; i += 256) Ws[i] = W[k0 * 128 + i];
        __syncthreads();
#pragma unroll 8
        for (int k = 0; k < 32; k++) {
            float wv = Ws[k * 128 + c];
#pragma unroll
            for (int r = 0; r < 8; r++) acc[r] += xs[(half * 8 + r) * K + k0 + k] * wv;
        }
    }
#pragma unroll
    for (int r = 0; r < 8; r++) {
        int row = row0 + half * 8 + r;
        if (row < N) out[(size_t)row * 128 + c] = acc[r];
    }
}

// per-node attention scalars
__global__ __launch_bounds__(256) void acompute_kernel(const float* __restrict__ h,
                                                       const float* __restrict__ att_s,
                                                       const float* __restrict__ att_d,
                                                       float* __restrict__ a_src,
                                                       float* __restrict__ a_dst, int N) {
    int node = blockIdx.x * 4 + (threadIdx.x >> 6);
    int lane = threadIdx.x & 63;
    if (node >= N) return;
    float v0 = h[(size_t)node * 128 + lane];
    float v1 = h[(size_t)node * 128 + 64 + lane];
    float s0 = v0 * att_s[lane];
    float s1 = v1 * att_s[64 + lane];
    float d0 = v0 * att_d[lane];
    float d1 = v1 * att_d[64 + lane];
    for (int off = 32; off; off >>= 1) {
        s0 += __shfl_xor(s0, off);
        s1 += __shfl_xor(s1, off);
        d0 += __shfl_xor(d0, off);
        d1 += __shfl_xor(d1, off);
    }
    if (lane == 0) {
        a_src[node * 2] = s0;
        a_src[node * 2 + 1] = s1;
        a_dst[node * 2] = d0;
        a_dst[node * 2 + 1] = d1;
    }
}

// ---------------- CSR build (once per call; graph shared by both layers) ----------------
__global__ __launch_bounds__(256) void init_deg(int* __restrict__ deg, int N) {
    int n = blockIdx.x * 256 + threadIdx.x;
    if (n < N) deg[n] = 1;  // self-loop
}

__global__ __launch_bounds__(256) void deg_hist(const int* __restrict__ ei, int E_in,
                                                int* __restrict__ deg) {
    int e = blockIdx.x * 256 + threadIdx.x;
    if (e < E_in) atomicAdd(&deg[ei[E_in + e]], 1);
}

// exclusive scan of deg[0..N) -> rowptr, 3 phases. 1024 elements / block.
__global__ __launch_bounds__(256) void scan_block(const int* __restrict__ deg, int N,
                                                  int* __restrict__ rowptr,
                                                  int* __restrict__ bsum) {
    __shared__ int ts[256];
    int base = blockIdx.x * 1024 + threadIdx.x * 4;
    int v[4];
    int s = 0;
#pragma unroll
    for (int j = 0; j < 4; j++) {
        int idx = base + j;
        v[j] = (idx < N) ? deg[idx] : 0;
        s += v[j];
    }
    ts[threadIdx.x] = s;
    __syncthreads();
    for (int off = 1; off < 256; off <<= 1) {
        int t = (threadIdx.x >= off) ? ts[threadIdx.x - off] : 0;
        __syncthreads();
        ts[threadIdx.x] += t;
        __syncthreads();
    }
    int run = (threadIdx.x > 0) ? ts[threadIdx.x - 1] : 0;
#pragma unroll
    for (int j = 0; j < 4; j++) {
        int idx = base + j;
        if (idx < N) rowptr[idx] = run;
        run += v[j];
    }
    if (threadIdx.x == 255) bsum[blockIdx.x] = ts[255];
}

__global__ __launch_bounds__(256) void scan_mid(int* __restrict__ bsum, int nb) {
    __shared__ int ts[256];
    int v = (threadIdx.x < nb) ? bsum[threadIdx.x] : 0;
    ts[threadIdx.x] = v;
    __syncthreads();
    for (int off = 1; off < 256; off <<= 1) {
        int t = (threadIdx.x >= off) ? ts[threadIdx.x - off] : 0;
        __syncthreads();
        ts[threadIdx.x] += t;
        __syncthreads();
    }
    int excl = (threadIdx.x > 0) ? ts[threadIdx.x - 1] : 0;
    if (threadIdx.x < nb) bsum[threadIdx.x] = excl;
}

__global__ __launch_bounds__(256) void scan_add(int* __restrict__ rowptr, int N,
                                                const int* __restrict__ bsum, int E_tot) {
    int i = blockIdx.x * 256 + threadIdx.x;
    if (i < N) rowptr[i] += bsum[i >> 10];
    if (i == N) rowptr[N] = E_tot;
}

__global__ __launch_bounds__(256) void csr_fill(const int* __restrict__ ei, int E_in, int N,
                                                const int* __restrict__ rowptr,
                                                int* __restrict__ cursor,
                                                int* __restrict__ ebuf) {
    int e = blockIdx.x * 256 + threadIdx.x;
    if (e < E_in) {
        int s = ei[e], d = ei[E_in + e];
        int p = atomicAdd(&cursor[d], 1);
        ebuf[rowptr[d] + p] = s;
    } else if (e < E_in + N) {
        int n = e - E_in;
        int p = atomicAdd(&cursor[n], 1);
        ebuf[rowptr[n] + p] = n;
    }
}

// ---------------- fused softmax + aggregate + head-mean + bias + ELU (+ final linear) ------
// one 64-lane wave per dst node; lane owns channel `lane` of head0 and head1.
template <int FINAL>
__global__ __launch_bounds__(256) void gat_accum(const int* __restrict__ rowptr,
                                                 const int* __restrict__ ebuf,
                                                 const float* __restrict__ a_src,
                                                 const float* __restrict__ a_dst,
                                                 const float* __restrict__ h,
                                                 const float* __restrict__ bias,
                                                 const float* __restrict__ lin_w,
                                                 const float* __restrict__ lin_b,
                                                 float* __restrict__ out, int N) {
    int n = blockIdx.x * 4 + (threadIdx.x >> 6);
    int lane = threadIdx.x & 63;
    if (n >= N) return;
    int beg = rowptr[n], end = rowptr[n + 1];
    float ad0 = a_dst[n * 2], ad1 = a_dst[n * 2 + 1];
    // pass A: per-head max logit (edges in parallel across lanes)
    float m0 = -1e30f, m1 = -1e30f;
    for (int i = beg + lane; i < end; i += 64) {
        int s = ebuf[i];
        float l0 = a_src[s * 2] + ad0;
        l0 = l0 > 0.f ? l0 : NEG * l0;
        float l1 = a_src[s * 2 + 1] + ad1;
        l1 = l1 > 0.f ? l1 : NEG * l1;
        m0 = fmaxf(m0, l0);
        m1 = fmaxf(m1, l1);
    }
    for (int off = 32; off; off >>= 1) {
        m0 = fmaxf(m0, __shfl_xor(m0, off));
        m1 = fmaxf(m1, __shfl_xor(m1, off));
    }
    // pass B: unnormalized weighted sum + denom
    float accA = 0.f, accB = 0.f, den0 = 0.f, den1 = 0.f;
    for (int i = beg; i < end; i++) {
        int s = ebuf[i];  // same addr across wave -> broadcast
        float l0 = a_src[s * 2] + ad0;
        l0 = l0 > 0.f ? l0 : NEG * l0;
        float l1 = a_src[s * 2 + 1] + ad1;
        l1 = l1 > 0.f ? l1 : NEG * l1;
        float e0 = expf(l0 - m0), e1 = expf(l1 - m1);
        den0 += e0;
        den1 += e1;
        accA = fmaf(e0, h[(size_t)s * 128 + lane], accA);
        accB = fmaf(e1, h[(size_t)s * 128 + 64 + lane], accB);
    }
    float v = 0.5f * (accA / (den0 + FEPS) + accB / (den1 + FEPS)) + bias[lane];
    v = v > 0.f ? v : expf(v) - 1.f;  // ELU
    if (FINAL) {
        float p = v * lin_w[lane];
        for (int off = 32; off; off >>= 1) p += __shfl_xor(p, off);
        if (lane == 0) out[n] = p + lin_b[0];
    } else {
        out[(size_t)n * 64 + lane] = v;
    }
}

extern "C" void kernel_launch(void* const* d_in, const int* in_sizes, int n_in,
                              void* d_out, int out_size, void* d_ws, size_t ws_size,
                              hipStream_t stream) {
    const float* x = (const float*)d_in[0];
    const int* ei = (const int*)d_in[1];
    const float* W1 = (const float*)d_in[2];
    const float* as1 = (const float*)d_in[3];
    const float* ad1 = (const float*)d_in[4];
    const float* b1 = (const float*)d_in[5];
    const float* W2 = (const float*)d_in[6];
    const float* as2 = (const float*)d_in[7];
    const float* ad2 = (const float*)d_in[8];
    const float* b2 = (const float*)d_in[9];
    const float* lin_w = (const float*)d_in[10];
    const float* lin_b = (const float*)d_in[11];
    float* out = (float*)d_out;

    const int N = NNODES;
    const int E_in = in_sizes[1] / 2;
    const int E_tot = E_in + N;

    char* ws = (char*)d_ws;
    size_t off = 0;
    auto alloc = [&](size_t bytes) {
        void* p = ws + off;
        off += (bytes + 255) & ~(size_t)255;
        return p;
    };
    float* h = (float*)alloc((size_t)N * 128 * 4);
    float* x2 = (float*)alloc((size_t)N * 64 * 4);
    float* a_src = (float*)alloc((size_t)N * 2 * 4);
    float* a_dst = (float*)alloc((size_t)N * 2 * 4);
    int* deg = (int*)alloc((size_t)N * 4);
    int* rowptr = (int*)alloc((size_t)(N + 1) * 4);
    int* cursor = (int*)alloc((size_t)N * 4);
    int* bsum = (int*)alloc(256 * 4);
    int* ebuf = (int*)alloc((size_t)E_tot * 4);

    const int scan_nb = (N + 1023) / 1024;

    // ---- CSR build (shared by both layers) ----
    hipLaunchKernelGGL(init_deg, dim3((N + 255) / 256), dim3(256), 0, stream, deg, N);
    hipMemsetAsync(cursor, 0, (size_t)N * 4, stream);
    hipLaunchKernelGGL(deg_hist, dim3((E_in + 255) / 256), dim3(256), 0, stream, ei, E_in, deg);
    hipLaunchKernelGGL(scan_block, dim3(scan_nb), dim3(256), 0, stream, deg, N, rowptr, bsum);
    hipLaunchKernelGGL(scan_mid, dim3(1), dim3(256), 0, stream, bsum, scan_nb);
    hipLaunchKernelGGL(scan_add, dim3((N + 256) / 256), dim3(256), 0, stream, rowptr, N, bsum,
                       E_tot);
    hipLaunchKernelGGL(csr_fill, dim3((E_in + N + 255) / 256), dim3(256), 0, stream, ei, E_in, N,
                       rowptr, cursor, ebuf);

    // ---- layer 1 ----
    hipLaunchKernelGGL((gemm_kernel<128>), dim3((N + 15) / 16), dim3(256), 0, stream, x, W1, h, N);
    hipLaunchKernelGGL(acompute_kernel, dim3((N + 3) / 4), dim3(256), 0, stream, h, as1, ad1,
                       a_src, a_dst, N);
    hipLaunchKernelGGL((gat_accum<0>), dim3((N + 3) / 4), dim3(256), 0, stream, rowptr, ebuf,
                       a_src, a_dst, h, b1, (const float*)nullptr, (const float*)nullptr, x2, N);

    // ---- layer 2 ----
    hipLaunchKernelGGL((gemm_kernel<64>), dim3((N + 15) / 16), dim3(256), 0, stream, x2, W2, h, N);
    hipLaunchKernelGGL(acompute_kernel, dim3((N + 3) / 4), dim3(256), 0, stream, h, as2, ad2,
                       a_src, a_dst, N);
    hipLaunchKernelGGL((gat_accum<1>), dim3((N + 3) / 4), dim3(256), 0, stream, rowptr, ebuf,
                       a_src, a_dst, h, b2, lin_w, lin_b, out, N);
}

// Round 4
// 608.801 us; speedup vs baseline: 4.0004x; 1.4766x over previous
//
#include <hip/hip_runtime.h>
#include <hip/hip_bf16.h>
#include <hip/hip_fp16.h>

#define NNODES 100000
#define NEG 0.2f
#define FEPS 1e-16f

// ---------------- GEMM: A [N x K] * W [K x 128] -> out [N x 128] ----------------
// 32-row x 128-col tile per block, 4x4 register blocking per thread.
template <int K>
__global__ __launch_bounds__(256) void gemm_kernel(const float* __restrict__ A,
                                                   const float* __restrict__ W,
                                                   float* __restrict__ out, int N) {
    const int Kc = 32;
    __shared__ float Ws[Kc * 128];
    __shared__ float xs[32 * Kc];  // [row][k]
    const int tid = threadIdx.x;
    const int tx = tid & 31;   // col group: cols 4*tx .. 4*tx+3
    const int ty = tid >> 5;   // row group: rows 4*ty .. 4*ty+3
    const int row0 = blockIdx.x * 32;
    float acc[4][4];
#pragma unroll
    for (int r = 0; r < 4; r++)
#pragma unroll
        for (int c = 0; c < 4; c++) acc[r][c] = 0.f;

    for (int k0 = 0; k0 < K; k0 += Kc) {
        __syncthreads();
        for (int i = tid; i < Kc * 128; i += 256) Ws[i] = W[k0 * 128 + i];
        {
            int r = tid >> 3;
            int kk = (tid & 7) * 4;
            int row = row0 + r;
            float4 av = make_float4(0.f, 0.f, 0.f, 0.f);
            if (row < N) av = *(const float4*)&A[(size_t)row * K + k0 + kk];
            *(float4*)&xs[r * Kc + kk] = av;
        }
        __syncthreads();
#pragma unroll 8
        for (int k = 0; k < Kc; k++) {
            float4 wv = *(float4*)&Ws[k * 128 + tx * 4];
            float x0 = xs[(ty * 4 + 0) * Kc + k];
            float x1 = xs[(ty * 4 + 1) * Kc + k];
            float x2 = xs[(ty * 4 + 2) * Kc + k];
            float x3 = xs[(ty * 4 + 3) * Kc + k];
            acc[0][0] = fmaf(x0, wv.x, acc[0][0]);
            acc[0][1] = fmaf(x0, wv.y, acc[0][1]);
            acc[0][2] = fmaf(x0, wv.z, acc[0][2]);
            acc[0][3] = fmaf(x0, wv.w, acc[0][3]);
            acc[1][0] = fmaf(x1, wv.x, acc[1][0]);
            acc[1][1] = fmaf(x1, wv.y, acc[1][1]);
            acc[1][2] = fmaf(x1, wv.z, acc[1][2]);
            acc[1][3] = fmaf(x1, wv.w, acc[1][3]);
            acc[2][0] = fmaf(x2, wv.x, acc[2][0]);
            acc[2][1] = fmaf(x2, wv.y, acc[2][1]);
            acc[2][2] = fmaf(x2, wv.z, acc[2][2]);
            acc[2][3] = fmaf(x2, wv.w, acc[2][3]);
            acc[3][0] = fmaf(x3, wv.x, acc[3][0]);
            acc[3][1] = fmaf(x3, wv.y, acc[3][1]);
            acc[3][2] = fmaf(x3, wv.z, acc[3][2]);
            acc[3][3] = fmaf(x3, wv.w, acc[3][3]);
        }
    }
#pragma unroll
    for (int r = 0; r < 4; r++) {
        int row = row0 + ty * 4 + r;
        if (row < N) *(float4*)&out[(size_t)row * 128 + tx * 4] =
            make_float4(acc[r][0], acc[r][1], acc[r][2], acc[r][3]);
    }
}

// ---------------- fused fp16-pack + attention scalars ----------------
// hp[n][c] = (fp16(h[n][c]), fp16(h[n][64+c])) packed in one uint.
__global__ __launch_bounds__(256) void pack_acompute_kernel(const float* __restrict__ h,
                                                            const float* __restrict__ att_s,
                                                            const float* __restrict__ att_d,
                                                            unsigned* __restrict__ hp,
                                                            float* __restrict__ a_src,
                                                            float* __restrict__ a_dst, int N) {
    int node = blockIdx.x * 4 + (threadIdx.x >> 6);
    int lane = threadIdx.x & 63;
    if (node >= N) return;
    float v0 = h[(size_t)node * 128 + lane];
    float v1 = h[(size_t)node * 128 + 64 + lane];
    unsigned u = ((unsigned)__half_as_ushort(__float2half(v1)) << 16) |
                 (unsigned)__half_as_ushort(__float2half(v0));
    hp[(size_t)node * 64 + lane] = u;
    float s0 = v0 * att_s[lane];
    float s1 = v1 * att_s[64 + lane];
    float d0 = v0 * att_d[lane];
    float d1 = v1 * att_d[64 + lane];
    for (int off = 32; off; off >>= 1) {
        s0 += __shfl_xor(s0, off);
        s1 += __shfl_xor(s1, off);
        d0 += __shfl_xor(d0, off);
        d1 += __shfl_xor(d1, off);
    }
    if (lane == 0) {
        a_src[node * 2] = s0;
        a_src[node * 2 + 1] = s1;
        a_dst[node * 2] = d0;
        a_dst[node * 2 + 1] = d1;
    }
}

// ---------------- CSR build (once per call; graph shared by both layers) ----------------
__global__ __launch_bounds__(256) void init_deg(int* __restrict__ deg, int N) {
    int n = blockIdx.x * 256 + threadIdx.x;
    if (n < N) deg[n] = 1;  // self-loop
}

__global__ __launch_bounds__(256) void deg_hist(const int* __restrict__ ei, int E_in,
                                                int* __restrict__ deg) {
    int e = blockIdx.x * 256 + threadIdx.x;
    if (e < E_in) atomicAdd(&deg[ei[E_in + e]], 1);
}

__global__ __launch_bounds__(256) void scan_block(const int* __restrict__ deg, int N,
                                                  int* __restrict__ rowptr,
                                                  int* __restrict__ bsum) {
    __shared__ int ts[256];
    int base = blockIdx.x * 1024 + threadIdx.x * 4;
    int v[4];
    int s = 0;
#pragma unroll
    for (int j = 0; j < 4; j++) {
        int idx = base + j;
        v[j] = (idx < N) ? deg[idx] : 0;
        s += v[j];
    }
    ts[threadIdx.x] = s;
    __syncthreads();
    for (int off = 1; off < 256; off <<= 1) {
        int t = (threadIdx.x >= off) ? ts[threadIdx.x - off] : 0;
        __syncthreads();
        ts[threadIdx.x] += t;
        __syncthreads();
    }
    int run = (threadIdx.x > 0) ? ts[threadIdx.x - 1] : 0;
#pragma unroll
    for (int j = 0; j < 4; j++) {
        int idx = base + j;
        if (idx < N) rowptr[idx] = run;
        run += v[j];
    }
    if (threadIdx.x == 255) bsum[blockIdx.x] = ts[255];
}

__global__ __launch_bounds__(256) void scan_mid(int* __restrict__ bsum, int nb) {
    __shared__ int ts[256];
    int v = (threadIdx.x < nb) ? bsum[threadIdx.x] : 0;
    ts[threadIdx.x] = v;
    __syncthreads();
    for (int off = 1; off < 256; off <<= 1) {
        int t = (threadIdx.x >= off) ? ts[threadIdx.x - off] : 0;
        __syncthreads();
        ts[threadIdx.x] += t;
        __syncthreads();
    }
    int excl = (threadIdx.x > 0) ? ts[threadIdx.x - 1] : 0;
    if (threadIdx.x < nb) bsum[threadIdx.x] = excl;
}

__global__ __launch_bounds__(256) void scan_add(int* __restrict__ rowptr, int N,
                                                const int* __restrict__ bsum, int E_tot) {
    int i = blockIdx.x * 256 + threadIdx.x;
    if (i < N) rowptr[i] += bsum[i >> 10];
    if (i == N) rowptr[N] = E_tot;
}

__global__ __launch_bounds__(256) void csr_fill(const int* __restrict__ ei, int E_in, int N,
                                                const int* __restrict__ rowptr,
                                                int* __restrict__ cursor,
                                                int* __restrict__ ebuf) {
    int e = blockIdx.x * 256 + threadIdx.x;
    if (e < E_in) {
        int s = ei[e], d = ei[E_in + e];
        int p = atomicAdd(&cursor[d], 1);
        ebuf[rowptr[d] + p] = s;
    } else if (e < E_in + N) {
        int n = e - E_in;
        int p = atomicAdd(&cursor[n], 1);
        ebuf[rowptr[n] + p] = n;
    }
}

// ---------------- fused softmax + aggregate + head-mean + bias + ELU (+ final linear) ------
// one 64-lane wave per dst node; lane owns channel `lane` of both heads (packed fp16).
template <int FINAL>
__global__ __launch_bounds__(256) void gat_accum(const int* __restrict__ rowptr,
                                                 const int* __restrict__ ebuf,
                                                 const float* __restrict__ a_src,
                                                 const float* __restrict__ a_dst,
                                                 const unsigned* __restrict__ hp,
                                                 const float* __restrict__ bias,
                                                 const float* __restrict__ lin_w,
                                                 const float* __restrict__ lin_b,
                                                 float* __restrict__ out, int N) {
    __shared__ float4 els[4][64];
    int w = threadIdx.x >> 6;
    int n = blockIdx.x * 4 + w;
    int lane = threadIdx.x & 63;
    if (n >= N) return;
    int beg = rowptr[n], end = rowptr[n + 1];
    float ad0 = a_dst[n * 2], ad1 = a_dst[n * 2 + 1];

    // pass A: per-head max logit (edges in parallel across lanes)
    float m0 = -1e30f, m1 = -1e30f;
    for (int i = beg + lane; i < end; i += 64) {
        int s = ebuf[i];
        float l0 = a_src[s * 2] + ad0;
        l0 = l0 > 0.f ? l0 : NEG * l0;
        float l1 = a_src[s * 2 + 1] + ad1;
        l1 = l1 > 0.f ? l1 : NEG * l1;
        m0 = fmaxf(m0, l0);
        m1 = fmaxf(m1, l1);
    }
    for (int off = 32; off; off >>= 1) {
        m0 = fmaxf(m0, __shfl_xor(m0, off));
        m1 = fmaxf(m1, __shfl_xor(m1, off));
    }

    // pass B: chunked — parallel exp phase into LDS, then short serial accumulate
    float accA = 0.f, accB = 0.f, den0 = 0.f, den1 = 0.f;
    for (int chunk = beg; chunk < end; chunk += 64) {
        int i = chunk + lane;
        float e0 = 0.f, e1 = 0.f;
        int s = 0;
        if (i < end) {
            s = ebuf[i];
            float l0 = a_src[s * 2] + ad0;
            l0 = l0 > 0.f ? l0 : NEG * l0;
            float l1 = a_src[s * 2 + 1] + ad1;
            l1 = l1 > 0.f ? l1 : NEG * l1;
            e0 = expf(l0 - m0);
            e1 = expf(l1 - m1);
        }
        den0 += e0;
        den1 += e1;
        els[w][lane] = make_float4(e0, e1, __int_as_float(s), 0.f);
        int cnt = end - chunk;
        if (cnt > 64) cnt = 64;
        for (int j = 0; j < cnt; j++) {
            float4 t = els[w][j];  // wave-broadcast
            int sj = __float_as_int(t.z);
            unsigned hv = hp[(size_t)sj * 64 + lane];
            float hA = __half2float(__ushort_as_half((unsigned short)(hv & 0xffffu)));
            float hB = __half2float(__ushort_as_half((unsigned short)(hv >> 16)));
            accA = fmaf(t.x, hA, accA);
            accB = fmaf(t.y, hB, accB);
        }
    }
    for (int off = 32; off; off >>= 1) {
        den0 += __shfl_xor(den0, off);
        den1 += __shfl_xor(den1, off);
    }

    float v = 0.5f * (accA / (den0 + FEPS) + accB / (den1 + FEPS)) + bias[lane];
    v = v > 0.f ? v : expf(v) - 1.f;  // ELU
    if (FINAL) {
        float p = v * lin_w[lane];
        for (int off = 32; off; off >>= 1) p += __shfl_xor(p, off);
        if (lane == 0) out[n] = p + lin_b[0];
    } else {
        out[(size_t)n * 64 + lane] = v;
    }
}

extern "C" void kernel_launch(void* const* d_in, const int* in_sizes, int n_in,
                              void* d_out, int out_size, void* d_ws, size_t ws_size,
                              hipStream_t stream) {
    const float* x = (const float*)d_in[0];
    const int* ei = (const int*)d_in[1];
    const float* W1 = (const float*)d_in[2];
    const float* as1 = (const float*)d_in[3];
    const float* ad1 = (const float*)d_in[4];
    const float* b1 = (const float*)d_in[5];
    const float* W2 = (const float*)d_in[6];
    const float* as2 = (const float*)d_in[7];
    const float* ad2 = (const float*)d_in[8];
    const float* b2 = (const float*)d_in[9];
    const float* lin_w = (const float*)d_in[10];
    const float* lin_b = (const float*)d_in[11];
    float* out = (float*)d_out;

    const int N = NNODES;
    const int E_in = in_sizes[1] / 2;
    const int E_tot = E_in + N;

    char* ws = (char*)d_ws;
    size_t off = 0;
    auto alloc = [&](size_t bytes) {
        void* p = ws + off;
        off += (bytes + 255) & ~(size_t)255;
        return p;
    };
    float* h = (float*)alloc((size_t)N * 128 * 4);
    unsigned* hp = (unsigned*)alloc((size_t)N * 64 * 4);
    float* x2 = (float*)alloc((size_t)N * 64 * 4);
    float* a_src = (float*)alloc((size_t)N * 2 * 4);
    float* a_dst = (float*)alloc((size_t)N * 2 * 4);
    int* deg = (int*)alloc((size_t)N * 4);
    int* rowptr = (int*)alloc((size_t)(N + 1) * 4);
    int* cursor = (int*)alloc((size_t)N * 4);
    int* bsum = (int*)alloc(256 * 4);
    int* ebuf = (int*)alloc((size_t)E_tot * 4);

    const int scan_nb = (N + 1023) / 1024;

    // ---- CSR build (shared by both layers) ----
    hipLaunchKernelGGL(init_deg, dim3((N + 255) / 256), dim3(256), 0, stream, deg, N);
    hipMemsetAsync(cursor, 0, (size_t)N * 4, stream);
    hipLaunchKernelGGL(deg_hist, dim3((E_in + 255) / 256), dim3(256), 0, stream, ei, E_in, deg);
    hipLaunchKernelGGL(scan_block, dim3(scan_nb), dim3(256), 0, stream, deg, N, rowptr, bsum);
    hipLaunchKernelGGL(scan_mid, dim3(1), dim3(256), 0, stream, bsum, scan_nb);
    hipLaunchKernelGGL(scan_add, dim3((N + 256) / 256), dim3(256), 0, stream, rowptr, N, bsum,
                       E_tot);
    hipLaunchKernelGGL(csr_fill, dim3((E_in + N + 255) / 256), dim3(256), 0, stream, ei, E_in, N,
                       rowptr, cursor, ebuf);

    // ---- layer 1 ----
    hipLaunchKernelGGL((gemm_kernel<128>), dim3((N + 31) / 32), dim3(256), 0, stream, x, W1, h, N);
    hipLaunchKernelGGL(pack_acompute_kernel, dim3((N + 3) / 4), dim3(256), 0, stream, h, as1, ad1,
                       hp, a_src, a_dst, N);
    hipLaunchKernelGGL((gat_accum<0>), dim3((N + 3) / 4), dim3(256), 0, stream, rowptr, ebuf,
                       a_src, a_dst, hp, b1, (const float*)nullptr, (const float*)nullptr, x2, N);

    // ---- layer 2 ----
    hipLaunchKernelGGL((gemm_kernel<64>), dim3((N + 31) / 32), dim3(256), 0, stream, x2, W2, h, N);
    hipLaunchKernelGGL(pack_acompute_kernel, dim3((N + 3) / 4), dim3(256), 0, stream, h, as2, ad2,
                       hp, a_src, a_dst, N);
    hipLaunchKernelGGL((gat_accum<1>), dim3((N + 3) / 4), dim3(256), 0, stream, rowptr, ebuf,
                       a_src, a_dst, hp, b2, lin_w, lin_b, out, N);
}